// Round 1
// 268.081 us; speedup vs baseline: 1.0125x; 1.0125x over previous
//
#include <hip/hip_runtime.h>
#include <hip/hip_bf16.h>
#include <math.h>

typedef __bf16 bf16;
typedef __bf16 bf16x8 __attribute__((ext_vector_type(8)));
typedef float  f32x4  __attribute__((ext_vector_type(4)));

#define MFMA16(a,b,c) __builtin_amdgcn_mfma_f32_16x16x32_bf16((a),(b),(c),0,0,0)
#define ATT_SCALE 0.0441941738241592f  /* 1/sqrt(512) */

// async global->LDS, 16 B/lane; LDS dest = wave-uniform base + lane*16
__device__ __forceinline__ void async16p(const void* g, void* l) {
    __builtin_amdgcn_global_load_lds((const __attribute__((address_space(1))) void*)g,
                                     (__attribute__((address_space(3))) void*)l,
                                     16, 0, 0);
}

// ---------------- prep: transpose 4 weights fp32[k][n] -> bf16 T[n][k] -----
__global__ __launch_bounds__(256) void prep_w_kernel(
    const float* __restrict__ Wq, const float* __restrict__ Wk,
    const float* __restrict__ Wv, const float* __restrict__ Wo,
    bf16* __restrict__ WqT, bf16* __restrict__ WkT,
    bf16* __restrict__ WvT, bf16* __restrict__ WoT)
{
    __shared__ float tile[32][33];
    const int bx = blockIdx.x;
    const float* W; bf16* T;
    switch (bx >> 8) {
      case 0: W=Wq; T=WqT; break;
      case 1: W=Wk; T=WkT; break;
      case 2: W=Wv; T=WvT; break;
      default: W=Wo; T=WoT; break;
    }
    const int rest = bx & 255;
    const int k0 = (rest & 15) * 32, n0 = (rest >> 4) * 32;
    const int tx = threadIdx.x & 31, ty = threadIdx.x >> 5;
    #pragma unroll
    for (int i=0;i<32;i+=8)
        tile[ty+i][tx] = W[(size_t)(k0+ty+i)*512 + n0+tx];
    __syncthreads();
    #pragma unroll
    for (int i=0;i<32;i+=8)
        T[(size_t)(n0+ty+i)*512 + k0+tx] = (bf16)tile[tx][ty+i];
}

// ------------- projection GEMM: fp32 A staged async, bf16 weights ----------
// z=0: q=Q@Wq+bq -> qbb ; z=1: k=K@Wk+bk -> kbb ; z=2: v=K@Wv+bv -> vT.
// 128x128 tile, BK=32, (256,3).
// NEW (this round): double-buffered LDS + 2-phase pipeline with counted
// vmcnt(6): loads for tile t+1 stay in flight across compute of tile t
// (raw s_barrier, never drains vmcnt to 0 in the main loop).  B-tile
// swizzle upgraded row&3 -> (row>>1)&3 (4-way -> 2-way bank aliasing).
__global__ __launch_bounds__(256, 3) void gemm_qkv_kernel(
    const float* __restrict__ Qf, const float* __restrict__ Kf,
    const bf16* __restrict__ WqT, const bf16* __restrict__ WkT,
    const bf16* __restrict__ WvT,
    const float* __restrict__ bq, const float* __restrict__ bk,
    const float* __restrict__ bv,
    bf16* __restrict__ qbb, bf16* __restrict__ kbb, bf16* __restrict__ vT)
{
    __shared__ __align__(16) char smem[49152];
    float* As32 = (float*)smem;            // 2 x (128x32 fp32 = 16 KB)
    bf16*  Bs   = (bf16*)(smem + 32768);   // 2 x (128x32 bf16 = 8 KB)
    bf16*  Lt   = (bf16*)smem;             // 64x128 bf16 (epilogue overlay, buf0)

    const int z = blockIdx.z;
    const float* A  = (z == 0) ? Qf  : Kf;
    const bf16*  BT = (z == 0) ? WqT : (z == 1) ? WkT : WvT;
    const float* bb = (z == 0) ? bq  : (z == 1) ? bk  : bv;

    const int m0 = blockIdx.x * 128, n0 = blockIdx.y * 128;
    const int tid = threadIdx.x;
    const int lane = tid & 63, wave = tid >> 6;
    const int qd = lane >> 4, lr = lane & 15;
    const int wm = (wave & 1) * 64, wn = (wave >> 1) * 64;

    // pre-swizzled global sources (LDS dest stays linear per-lane)
    const float* gA = A + (size_t)(m0 + (tid>>3))*512 + (((tid&7)^((tid>>3)&7))*4);
    const bf16*  gB = BT + (size_t)(n0 + (tid>>2))*512 + (((tid&3)^((tid>>3)&3))*8);

    f32x4 acc[4][4];
    #pragma unroll
    for (int i=0;i<4;i++)
      #pragma unroll
      for (int j=0;j<4;j++) acc[i][j] = (f32x4){0,0,0,0};

    auto stage = [&](int buf, int k0) {
        float* lA = As32 + buf*4096 + wave*256;
        bf16*  lB = Bs   + buf*4096 + wave*512;
        #pragma unroll
        for (int i=0;i<4;i++)
            async16p(gA + k0 + (size_t)i*32*512, lA + i*1024);
        async16p(gB + k0,                  lB);
        async16p(gB + k0 + (size_t)64*512, lB + 2048);
    };

    stage(0, 0);                            // 6 loads in flight
    for (int t = 0; t < 16; ++t) {
        const int cur = t & 1;
        __builtin_amdgcn_sched_barrier(0);
        __builtin_amdgcn_s_barrier();       // all waves done reading buf[cur^1]
        if (t < 15) {
            stage(cur ^ 1, (t+1)*32);       // overwrite just-consumed buffer
            asm volatile("s_waitcnt vmcnt(6)" ::: "memory");  // tile t landed
        } else {
            asm volatile("s_waitcnt vmcnt(0)" ::: "memory");
        }
        __builtin_amdgcn_s_barrier();       // tile t visible to all waves

        const float* Ab = As32 + cur*4096;
        const bf16*  Bb = Bs   + cur*4096;
        bf16x8 af[4], bfr[4];
        #pragma unroll
        for (int mi=0;mi<4;mi++) {
            int row = wm + mi*16 + lr;
            f32x4 f0 = *(f32x4*)(Ab + row*32 + (((qd*2  )^(lr&7))*4));
            f32x4 f1 = *(f32x4*)(Ab + row*32 + (((qd*2+1)^(lr&7))*4));
            bf16x8 a;
            a[0]=(bf16)f0[0]; a[1]=(bf16)f0[1]; a[2]=(bf16)f0[2]; a[3]=(bf16)f0[3];
            a[4]=(bf16)f1[0]; a[5]=(bf16)f1[1]; a[6]=(bf16)f1[2]; a[7]=(bf16)f1[3];
            af[mi] = a;
        }
        #pragma unroll
        for (int ni=0;ni<4;ni++)
            bfr[ni] = *(bf16x8*)(Bb + (wn+ni*16+lr)*32 + ((qd^((lr>>1)&3))*8));
        #pragma unroll
        for (int mi=0;mi<4;mi++)
          #pragma unroll
          for (int ni=0;ni<4;ni++)
            acc[mi][ni] = MFMA16(af[mi], bfr[ni], acc[mi][ni]);
    }

    if (z < 2) {   // q or k: direct bf16 row-major write
        bf16* C = (z == 0) ? qbb : kbb;
        #pragma unroll
        for (int ni=0;ni<4;ni++) {
            int n = n0 + wn + ni*16 + lr;
            float bv0 = bb[n];
            #pragma unroll
            for (int mi=0;mi<4;mi++) {
                int mb = m0 + wm + mi*16 + qd*4;
                #pragma unroll
                for (int r=0;r<4;r++)
                    C[(size_t)(mb+r)*512 + n] = (bf16)(acc[mi][ni][r] + bv0);
            }
        }
    } else {       // v: vT[b][h][d][tok] via swizzled LDS transpose
        const int b = m0 >> 10, tok0 = m0 & 1023;
        const int row = tid >> 2, ch = tid & 3;
        #pragma unroll
        for (int half = 0; half < 2; ++half) {
            __syncthreads();
            if ((wn >> 6) == half) {
                #pragma unroll
                for (int ni=0;ni<4;ni++) {
                    int nl = ni*16 + lr;
                    float bvv = bb[n0 + half*64 + nl];
                    #pragma unroll
                    for (int mi=0;mi<4;mi++)
                      #pragma unroll
                      for (int r=0;r<4;r++) {
                        int col = wm + mi*16 + qd*4 + r;
                        Lt[nl*128 + ((((col>>3)^(nl&7))<<3) | (col&7))]
                            = (bf16)(acc[mi][ni][r] + bvv);
                      }
                }
            }
            __syncthreads();
            const int h = (n0 >> 6) + half;
            bf16* dst = vT + ((size_t)((b*8 + h)*64 + row))*1024 + tok0 + ch*32;
            #pragma unroll
            for (int s=0;s<4;s++) {
                int g = (ch*4 + s) ^ (row & 7);
                *(uint4*)(dst + s*8) = *(uint4*)(Lt + row*128 + g*8);
            }
        }
    }
}

// ---------------- attention: r3 structure (measured best) + q-residual -----
__global__ __launch_bounds__(256, 4) void attn_kernel(
    const bf16* __restrict__ qb, const bf16* __restrict__ kb,
    const bf16* __restrict__ vT, bf16* __restrict__ attnb)
{
    const int qt = blockIdx.x, h = blockIdx.y, b = blockIdx.z;
    const int tid = threadIdx.x, lane = tid & 63, wave = tid >> 6;
    const int qd = lane >> 4, lr = lane & 15;
    const int q0 = qt*128 + wave*32;

    __shared__ bf16 Ks[64][72];      // [key][d]
    __shared__ bf16 Vs[64][72];      // [d][key]
    __shared__ bf16 Pl[4][32][72];   // per-wave P round-trip (C->A layout)

    bf16x8 aq[2][2];
    #pragma unroll
    for (int mi=0;mi<2;mi++) {
        const bf16* qrow = qb + ((size_t)(b*1024 + q0 + mi*16 + lr))*512 + h*64;
        aq[mi][0] = *(const bf16x8*)(qrow + qd*8);
        aq[mi][1] = *(const bf16x8*)(qrow + 32 + qd*8);
    }

    const int srow = tid >> 2;
    const int scol = (tid & 3) * 16;
    const bf16* kgp = kb + ((size_t)(b*1024 + srow))*512 + h*64 + scol;
    const bf16* vgp = vT + ((size_t)((b*8 + h)*64 + srow))*1024 + scol;

    uint4 k0r = *(const uint4*)(kgp);
    uint4 k1r = *(const uint4*)(kgp + 8);
    uint4 v0r = *(const uint4*)(vgp);
    uint4 v1r = *(const uint4*)(vgp + 8);

    f32x4 acc[2][4];
    #pragma unroll
    for (int mi=0;mi<2;mi++)
      #pragma unroll
      for (int ni=0;ni<4;ni++) acc[mi][ni] = (f32x4){0,0,0,0};
    float l[2][4] = {{0,0,0,0},{0,0,0,0}};

    for (int t=0; t<16; ++t) {
        __syncthreads();
        *(uint4*)(&Ks[srow][scol])   = k0r;
        *(uint4*)(&Ks[srow][scol+8]) = k1r;
        *(uint4*)(&Vs[srow][scol])   = v0r;
        *(uint4*)(&Vs[srow][scol+8]) = v1r;
        __syncthreads();
        if (t < 15) {   // prefetch next tile; overlaps compute below
            const size_t kk = (size_t)(t+1)*64;
            k0r = *(const uint4*)(kgp + kk*512);
            k1r = *(const uint4*)(kgp + kk*512 + 8);
            v0r = *(const uint4*)(vgp + kk);
            v1r = *(const uint4*)(vgp + kk + 8);
        }

        f32x4 s[2][4];
        #pragma unroll
        for (int mi=0;mi<2;mi++)
          #pragma unroll
          for (int ni=0;ni<4;ni++) s[mi][ni] = (f32x4){0,0,0,0};
        #pragma unroll
        for (int ni=0;ni<4;ni++) {
            bf16x8 b0 = *(bf16x8*)(&Ks[ni*16+lr][qd*8]);
            bf16x8 b1 = *(bf16x8*)(&Ks[ni*16+lr][32+qd*8]);
            #pragma unroll
            for (int mi=0;mi<2;mi++) {
                s[mi][ni] = MFMA16(aq[mi][0], b0, s[mi][ni]);
                s[mi][ni] = MFMA16(aq[mi][1], b1, s[mi][ni]);
            }
        }
        #pragma unroll
        for (int mi=0;mi<2;mi++)
          #pragma unroll
          for (int ni=0;ni<4;ni++)
            #pragma unroll
            for (int r=0;r<4;r++) {
                float pv = __expf(s[mi][ni][r] * ATT_SCALE);
                s[mi][ni][r] = pv;
                l[mi][r] += pv;
            }
        #pragma unroll
        for (int mi=0;mi<2;mi++)
          #pragma unroll
          for (int ni=0;ni<4;ni++)
            #pragma unroll
            for (int r=0;r<4;r++)
                Pl[wave][mi*16 + qd*4 + r][ni*16 + lr] = (bf16)s[mi][ni][r];
        bf16x8 ap[2][2];
        #pragma unroll
        for (int mi=0;mi<2;mi++) {
            ap[mi][0] = *(bf16x8*)(&Pl[wave][mi*16+lr][qd*8]);
            ap[mi][1] = *(bf16x8*)(&Pl[wave][mi*16+lr][32+qd*8]);
        }
        #pragma unroll
        for (int ni=0;ni<4;ni++) {
            bf16x8 v0 = *(bf16x8*)(&Vs[ni*16+lr][qd*8]);
            bf16x8 v1 = *(bf16x8*)(&Vs[ni*16+lr][32+qd*8]);
            #pragma unroll
            for (int mi=0;mi<2;mi++) {
                acc[mi][ni] = MFMA16(ap[mi][0], v0, acc[mi][ni]);
                acc[mi][ni] = MFMA16(ap[mi][1], v1, acc[mi][ni]);
            }
        }
    }

    #pragma unroll
    for (int off=1; off<16; off<<=1)
      #pragma unroll
      for (int mi=0;mi<2;mi++)
        #pragma unroll
        for (int r=0;r<4;r++) l[mi][r] += __shfl_xor(l[mi][r], off);

    // epilogue: normalize, transpose via Pl, add q (residual), store bf16x8
    #pragma unroll
    for (int mi=0;mi<2;mi++) {
        float inv[4];
        #pragma unroll
        for (int r=0;r<4;r++) inv[r] = 1.f / l[mi][r];
        #pragma unroll
        for (int ni=0;ni<4;ni++)
          #pragma unroll
          for (int r=0;r<4;r++)
            Pl[wave][qd*4+r][ni*16+lr] = (bf16)(acc[mi][ni][r] * inv[r]);
        bf16x8 oA = *(bf16x8*)(&Pl[wave][lr][qd*8]);
        bf16x8 oB = *(bf16x8*)(&Pl[wave][lr][32+qd*8]);
        bf16x8 rA, rB;
        #pragma unroll
        for (int j=0;j<8;j++) {
            rA[j] = (bf16)((float)oA[j] + (float)aq[mi][0][j]);
            rB[j] = (bf16)((float)oB[j] + (float)aq[mi][1][j]);
        }
        bf16* dst = attnb + ((size_t)(b*1024 + q0 + mi*16 + lr))*512 + h*64;
        *(bf16x8*)(dst + qd*8)      = rA;
        *(bf16x8*)(dst + 32 + qd*8) = rB;
    }
}

// ---------------- ln0: Obf = LN(attnb)  (attnb already holds q+attn) -------
__global__ __launch_bounds__(256) void ln0_kernel(
    const bf16* __restrict__ attnb, bf16* __restrict__ Obf)
{
    const int wave = threadIdx.x >> 6, lane = threadIdx.x & 63;
    const int row = blockIdx.x*4 + wave;
    const size_t base = (size_t)row*512 + lane*8;
    bf16x8 av = *(const bf16x8*)(attnb + base);
    float x[8];
    #pragma unroll
    for (int i=0;i<8;i++) x[i] = (float)av[i];
    float s1 = 0.f, s2 = 0.f;
    #pragma unroll
    for (int i=0;i<8;i++){ s1 += x[i]; s2 += x[i]*x[i]; }
    #pragma unroll
    for (int off=1; off<64; off<<=1) { s1 += __shfl_xor(s1, off); s2 += __shfl_xor(s2, off); }
    float mu  = s1 * (1.f/512.f);
    float var = s2 * (1.f/512.f) - mu*mu;
    float rstd = rsqrtf(var + 1e-5f);
    bf16x8 ob;
    #pragma unroll
    for (int i=0;i<8;i++) ob[i] = (bf16)((x[i]-mu)*rstd);
    *(bf16x8*)(Obf + base) = ob;
}

// -------- shared GEMM K-loop: 128x128 tile, now BK=32 double-buffered ------
// 2-phase pipeline with counted vmcnt(4); (row>>1)&3 swizzle (2-way banks).
__device__ __forceinline__ void gemm_core(
    const bf16* __restrict__ A, const bf16* __restrict__ BT,
    int m0, int n0, char* smem, f32x4 (&acc)[4][4])
{
    bf16* As = (bf16*)smem;            // 2 x (128x32 = 8 KB)
    bf16* Bs = (bf16*)(smem + 16384);  // 2 x (128x32 = 8 KB)
    const int tid = threadIdx.x;
    const int lane = tid & 63, wave = tid >> 6;
    const int qd = lane >> 4, lr = lane & 15;
    const int wm = (wave & 1) * 64, wn = (wave >> 1) * 64;

    const int srow = tid >> 2;                            // 0..63
    const int sgr  = ((tid & 3) ^ ((tid >> 3) & 3)) * 8;  // pre-swizzled granule
    const bf16* gA = A  + (size_t)(m0 + srow)*512 + sgr;
    const bf16* gB = BT + (size_t)(n0 + srow)*512 + sgr;

    auto stage = [&](int buf, int k0) {
        bf16* lA = As + buf*4096 + wave*512;
        bf16* lB = Bs + buf*4096 + wave*512;
        async16p(gA + k0,                  lA);
        async16p(gA + k0 + (size_t)64*512, lA + 2048);
        async16p(gB + k0,                  lB);
        async16p(gB + k0 + (size_t)64*512, lB + 2048);
    };

    stage(0, 0);
    for (int t = 0; t < 16; ++t) {
        const int cur = t & 1;
        __builtin_amdgcn_sched_barrier(0);
        __builtin_amdgcn_s_barrier();
        if (t < 15) {
            stage(cur ^ 1, (t+1)*32);
            asm volatile("s_waitcnt vmcnt(4)" ::: "memory");
        } else {
            asm volatile("s_waitcnt vmcnt(0)" ::: "memory");
        }
        __builtin_amdgcn_s_barrier();

        const bf16* Ab = As + cur*4096;
        const bf16* Bb = Bs + cur*4096;
        bf16x8 af[4], bfr[4];
        #pragma unroll
        for (int mi=0;mi<4;mi++)
            af[mi] = *(bf16x8*)(Ab + (wm+mi*16+lr)*32 + ((qd^((lr>>1)&3))*8));
        #pragma unroll
        for (int ni=0;ni<4;ni++)
            bfr[ni] = *(bf16x8*)(Bb + (wn+ni*16+lr)*32 + ((qd^((lr>>1)&3))*8));
        #pragma unroll
        for (int mi=0;mi<4;mi++)
          #pragma unroll
          for (int ni=0;ni<4;ni++)
            acc[mi][ni] = MFMA16(af[mi], bfr[ni], acc[mi][ni]);
    }
}

// ------- gemm_o: G = Obf@WoT + bo; xb = Obf + gelu(G)  (bf16 out) ----------
__global__ __launch_bounds__(256, 4) void gemm_o_kernel(
    const bf16* __restrict__ Obf, const bf16* __restrict__ WoT,
    const float* __restrict__ bo, bf16* __restrict__ xb)
{
    __shared__ __align__(16) char smem[32768];
    const int m0 = blockIdx.x * 128, n0 = blockIdx.y * 128;
    const int tid = threadIdx.x;
    const int lane = tid & 63, wave = tid >> 6;
    const int qd = lane >> 4, lr = lane & 15;
    const int wm = (wave & 1) * 64, wn = (wave >> 1) * 64;

    f32x4 acc[4][4];
    #pragma unroll
    for (int i=0;i<4;i++)
      #pragma unroll
      for (int j=0;j<4;j++) acc[i][j] = (f32x4){0,0,0,0};

    gemm_core(Obf, WoT, m0, n0, smem, acc);

    #pragma unroll
    for (int ni=0;ni<4;ni++) {
        int n = n0 + wn + ni*16 + lr;
        float bv = bo[n];
        #pragma unroll
        for (int mi=0;mi<4;mi++) {
            int mb = m0 + wm + mi*16 + qd*4;
            #pragma unroll
            for (int r=0;r<4;r++) {
                float g = acc[mi][ni][r] + bv;
                float gelu = 0.5f * g * (1.f + erff(g * 0.70710678118654752f));
                size_t idx = (size_t)(mb+r)*512 + n;
                xb[idx] = (bf16)((float)Obf[idx] + gelu);
            }
        }
    }
}

// ---------------- ln1: out = LN(xb) ----------------
__global__ __launch_bounds__(256) void ln1_kernel(
    const bf16* __restrict__ xb, float* __restrict__ out)
{
    const int wave = threadIdx.x >> 6, lane = threadIdx.x & 63;
    const int row = blockIdx.x*4 + wave;
    const size_t base = (size_t)row*512 + lane*8;
    bf16x8 xv = *(const bf16x8*)(xb + base);
    float x[8];
    #pragma unroll
    for (int i=0;i<8;i++) x[i] = (float)xv[i];
    float s1 = 0.f, s2 = 0.f;
    #pragma unroll
    for (int i=0;i<8;i++){ s1 += x[i]; s2 += x[i]*x[i]; }
    #pragma unroll
    for (int off=1; off<64; off<<=1) { s1 += __shfl_xor(s1, off); s2 += __shfl_xor(s2, off); }
    float mu  = s1 * (1.f/512.f);
    float var = s2 * (1.f/512.f) - mu*mu;
    float rstd = rsqrtf(var + 1e-5f);
    float4 o0 = {(x[0]-mu)*rstd,(x[1]-mu)*rstd,(x[2]-mu)*rstd,(x[3]-mu)*rstd};
    float4 o1 = {(x[4]-mu)*rstd,(x[5]-mu)*rstd,(x[6]-mu)*rstd,(x[7]-mu)*rstd};
    *(float4*)(out + base)     = o0;
    *(float4*)(out + base + 4) = o1;
}

extern "C" void kernel_launch(void* const* d_in, const int* in_sizes, int n_in,
                              void* d_out, int out_size, void* d_ws, size_t ws_size,
                              hipStream_t stream)
{
    (void)in_sizes; (void)n_in; (void)out_size; (void)ws_size;
    const float* Q  = (const float*)d_in[0];
    const float* K  = (const float*)d_in[1];
    const float* Wq = (const float*)d_in[2];
    const float* bq = (const float*)d_in[3];
    const float* Wk = (const float*)d_in[4];
    const float* bk = (const float*)d_in[5];
    const float* Wv = (const float*)d_in[6];
    const float* bv = (const float*)d_in[7];
    const float* Wo = (const float*)d_in[8];
    const float* bo = (const float*)d_in[9];
    float* out = (float*)d_out;

    const size_t nTok = (size_t)16*1024*512;
    char* p = (char*)d_ws;
    auto alloc = [&](size_t bytes)->char* {
        char* r = p; p += (bytes + 255) & ~(size_t)255; return r;
    };
    bf16* WqT   = (bf16*)alloc(512*512*2);
    bf16* WkT   = (bf16*)alloc(512*512*2);
    bf16* WvT   = (bf16*)alloc(512*512*2);
    bf16* WoT   = (bf16*)alloc(512*512*2);
    bf16* qbb   = (bf16*)alloc(nTok*2);
    bf16* kbb   = (bf16*)alloc(nTok*2);
    bf16* vT    = (bf16*)alloc(nTok*2);
    bf16* attnb = (bf16*)alloc(nTok*2);
    bf16* Obf   = (bf16*)alloc(nTok*2);
    bf16* xb    = (bf16*)alloc(nTok*2);

    prep_w_kernel<<<1024, 256, 0, stream>>>(Wq, Wk, Wv, Wo, WqT, WkT, WvT, WoT);
    gemm_qkv_kernel<<<dim3(128,4,3), 256, 0, stream>>>(Q, K, WqT, WkT, WvT,
                                                       bq, bk, bv, qbb, kbb, vT);
    attn_kernel<<<dim3(8,8,16), 256, 0, stream>>>(qbb, kbb, vT, attnb);
    ln0_kernel<<<4096, 256, 0, stream>>>(attnb, Obf);
    gemm_o_kernel<<<dim3(128,4), 256, 0, stream>>>(Obf, WoT, bo, xb);
    ln1_kernel<<<4096, 256, 0, stream>>>(xb, out);
}

// Round 2
// 257.428 us; speedup vs baseline: 1.0544x; 1.0414x over previous
//
#include <hip/hip_runtime.h>
#include <hip/hip_bf16.h>
#include <math.h>

typedef __bf16 bf16;
typedef __bf16 bf16x8 __attribute__((ext_vector_type(8)));
typedef float  f32x4  __attribute__((ext_vector_type(4)));
typedef float  f32x16 __attribute__((ext_vector_type(16)));
typedef unsigned u32x4 __attribute__((ext_vector_type(4)));

#define MFMA16(a,b,c) __builtin_amdgcn_mfma_f32_16x16x32_bf16((a),(b),(c),0,0,0)
#define MFMA32(a,b,c) __builtin_amdgcn_mfma_f32_32x32x16_bf16((a),(b),(c),0,0,0)
#define ATT_SCALE 0.0441941738241592f  /* 1/sqrt(512) */

// async global->LDS, 16 B/lane; LDS dest = wave-uniform base + lane*16
__device__ __forceinline__ void async16p(const void* g, void* l) {
    __builtin_amdgcn_global_load_lds((const __attribute__((address_space(1))) void*)g,
                                     (__attribute__((address_space(3))) void*)l,
                                     16, 0, 0);
}

// pack two f32 -> 2xbf16 in a u32 (compiler emits v_cvt_pk_bf16_f32)
__device__ __forceinline__ unsigned pkbf(float a, float b) {
    union { bf16 h[2]; unsigned u; } x;
    x.h[0] = (bf16)a; x.h[1] = (bf16)b; return x.u;
}

// swap 32-lane halves of two regs: a' = [a.lo | b.lo], b' = [a.hi | b.hi]
__device__ __forceinline__ void plswap(unsigned &a, unsigned &b) {
#if __has_builtin(__builtin_amdgcn_permlane32_swap)
    auto r = __builtin_amdgcn_permlane32_swap((int)a, (int)b, false, false);
    a = (unsigned)r[0]; b = (unsigned)r[1];
#else
    unsigned sa = (unsigned)__shfl_xor((int)a, 32);
    unsigned sb = (unsigned)__shfl_xor((int)b, 32);
    bool hi = (threadIdx.x & 32) != 0;
    unsigned na = hi ? sb : a;
    unsigned nb = hi ? b  : sa;
    a = na; b = nb;
#endif
}

// ---------------- prep: transpose 4 weights fp32[k][n] -> bf16 T[n][k] -----
__global__ __launch_bounds__(256) void prep_w_kernel(
    const float* __restrict__ Wq, const float* __restrict__ Wk,
    const float* __restrict__ Wv, const float* __restrict__ Wo,
    bf16* __restrict__ WqT, bf16* __restrict__ WkT,
    bf16* __restrict__ WvT, bf16* __restrict__ WoT)
{
    __shared__ float tile[32][33];
    const int bx = blockIdx.x;
    const float* W; bf16* T;
    switch (bx >> 8) {
      case 0: W=Wq; T=WqT; break;
      case 1: W=Wk; T=WkT; break;
      case 2: W=Wv; T=WvT; break;
      default: W=Wo; T=WoT; break;
    }
    const int rest = bx & 255;
    const int k0 = (rest & 15) * 32, n0 = (rest >> 4) * 32;
    const int tx = threadIdx.x & 31, ty = threadIdx.x >> 5;
    #pragma unroll
    for (int i=0;i<32;i+=8)
        tile[ty+i][tx] = W[(size_t)(k0+ty+i)*512 + n0+tx];
    __syncthreads();
    #pragma unroll
    for (int i=0;i<32;i+=8)
        T[(size_t)(n0+ty+i)*512 + k0+tx] = (bf16)tile[tx][ty+i];
}

// ------------- projection GEMM: fp32 A staged async, bf16 weights ----------
// (round-1 measured structure: dbuf LDS + counted vmcnt(6), kept as-is)
__global__ __launch_bounds__(256, 3) void gemm_qkv_kernel(
    const float* __restrict__ Qf, const float* __restrict__ Kf,
    const bf16* __restrict__ WqT, const bf16* __restrict__ WkT,
    const bf16* __restrict__ WvT,
    const float* __restrict__ bq, const float* __restrict__ bk,
    const float* __restrict__ bv,
    bf16* __restrict__ qbb, bf16* __restrict__ kbb, bf16* __restrict__ vT)
{
    __shared__ __align__(16) char smem[49152];
    float* As32 = (float*)smem;            // 2 x (128x32 fp32 = 16 KB)
    bf16*  Bs   = (bf16*)(smem + 32768);   // 2 x (128x32 bf16 = 8 KB)
    bf16*  Lt   = (bf16*)smem;             // 64x128 bf16 (epilogue overlay, buf0)

    const int z = blockIdx.z;
    const float* A  = (z == 0) ? Qf  : Kf;
    const bf16*  BT = (z == 0) ? WqT : (z == 1) ? WkT : WvT;
    const float* bb = (z == 0) ? bq  : (z == 1) ? bk  : bv;

    const int m0 = blockIdx.x * 128, n0 = blockIdx.y * 128;
    const int tid = threadIdx.x;
    const int lane = tid & 63, wave = tid >> 6;
    const int qd = lane >> 4, lr = lane & 15;
    const int wm = (wave & 1) * 64, wn = (wave >> 1) * 64;

    const float* gA = A + (size_t)(m0 + (tid>>3))*512 + (((tid&7)^((tid>>3)&7))*4);
    const bf16*  gB = BT + (size_t)(n0 + (tid>>2))*512 + (((tid&3)^((tid>>3)&3))*8);

    f32x4 acc[4][4];
    #pragma unroll
    for (int i=0;i<4;i++)
      #pragma unroll
      for (int j=0;j<4;j++) acc[i][j] = (f32x4){0,0,0,0};

    auto stage = [&](int buf, int k0) {
        float* lA = As32 + buf*4096 + wave*256;
        bf16*  lB = Bs   + buf*4096 + wave*512;
        #pragma unroll
        for (int i=0;i<4;i++)
            async16p(gA + k0 + (size_t)i*32*512, lA + i*1024);
        async16p(gB + k0,                  lB);
        async16p(gB + k0 + (size_t)64*512, lB + 2048);
    };

    stage(0, 0);
    for (int t = 0; t < 16; ++t) {
        const int cur = t & 1;
        __builtin_amdgcn_sched_barrier(0);
        __builtin_amdgcn_s_barrier();
        if (t < 15) {
            stage(cur ^ 1, (t+1)*32);
            asm volatile("s_waitcnt vmcnt(6)" ::: "memory");
        } else {
            asm volatile("s_waitcnt vmcnt(0)" ::: "memory");
        }
        __builtin_amdgcn_s_barrier();

        const float* Ab = As32 + cur*4096;
        const bf16*  Bb = Bs   + cur*4096;
        bf16x8 af[4], bfr[4];
        #pragma unroll
        for (int mi=0;mi<4;mi++) {
            int row = wm + mi*16 + lr;
            f32x4 f0 = *(f32x4*)(Ab + row*32 + (((qd*2  )^(lr&7))*4));
            f32x4 f1 = *(f32x4*)(Ab + row*32 + (((qd*2+1)^(lr&7))*4));
            bf16x8 a;
            a[0]=(bf16)f0[0]; a[1]=(bf16)f0[1]; a[2]=(bf16)f0[2]; a[3]=(bf16)f0[3];
            a[4]=(bf16)f1[0]; a[5]=(bf16)f1[1]; a[6]=(bf16)f1[2]; a[7]=(bf16)f1[3];
            af[mi] = a;
        }
        #pragma unroll
        for (int ni=0;ni<4;ni++)
            bfr[ni] = *(bf16x8*)(Bb + (wn+ni*16+lr)*32 + ((qd^((lr>>1)&3))*8));
        #pragma unroll
        for (int mi=0;mi<4;mi++)
          #pragma unroll
          for (int ni=0;ni<4;ni++)
            acc[mi][ni] = MFMA16(af[mi], bfr[ni], acc[mi][ni]);
    }

    if (z < 2) {
        bf16* C = (z == 0) ? qbb : kbb;
        #pragma unroll
        for (int ni=0;ni<4;ni++) {
            int n = n0 + wn + ni*16 + lr;
            float bv0 = bb[n];
            #pragma unroll
            for (int mi=0;mi<4;mi++) {
                int mb = m0 + wm + mi*16 + qd*4;
                #pragma unroll
                for (int r=0;r<4;r++)
                    C[(size_t)(mb+r)*512 + n] = (bf16)(acc[mi][ni][r] + bv0);
            }
        }
    } else {
        const int b = m0 >> 10, tok0 = m0 & 1023;
        const int row = tid >> 2, ch = tid & 3;
        #pragma unroll
        for (int half = 0; half < 2; ++half) {
            __syncthreads();
            if ((wn >> 6) == half) {
                #pragma unroll
                for (int ni=0;ni<4;ni++) {
                    int nl = ni*16 + lr;
                    float bvv = bb[n0 + half*64 + nl];
                    #pragma unroll
                    for (int mi=0;mi<4;mi++)
                      #pragma unroll
                      for (int r=0;r<4;r++) {
                        int col = wm + mi*16 + qd*4 + r;
                        Lt[nl*128 + ((((col>>3)^(nl&7))<<3) | (col&7))]
                            = (bf16)(acc[mi][ni][r] + bvv);
                      }
                }
            }
            __syncthreads();
            const int h = (n0 >> 6) + half;
            bf16* dst = vT + ((size_t)((b*8 + h)*64 + row))*1024 + tok0 + ch*32;
            #pragma unroll
            for (int s=0;s<4;s++) {
                int g = (ch*4 + s) ^ (row & 7);
                *(uint4*)(dst + s*8) = *(uint4*)(Lt + row*128 + g*8);
            }
        }
    }
}

// ---------------- attention: swapped-QK^T 32x32, in-register softmax -------
// Per wave: 32 q-rows. S^T = mfma32(K,Q) puts a full P-row per lane
// (q = lane&31): row-sum l is a per-lane scalar. P->A-frag via 16 pkbf +
// 8 permlane32_swap per tile (no Pl LDS round-trip). K/V staged by
// global_load_lds (dbuf, counted vmcnt(4)), XOR-granule swizzled layout.
// Grid flattened: qt = x>>7 so the 8 blocks sharing (b,h) K/V land on the
// same XCD, 128 ids apart (= the concurrent window) for L2 reuse.
__global__ __launch_bounds__(256, 4) void attn_kernel(
    const bf16* __restrict__ qb, const bf16* __restrict__ kb,
    const bf16* __restrict__ vT, bf16* __restrict__ attnb)
{
    const int x = blockIdx.x;
    const int qt = x >> 7, h = x & 7, b = (x & 127) >> 3;
    const int tid = threadIdx.x, lane = tid & 63, wave = tid >> 6;
    const int l = lane & 31, hi = lane >> 5;
    const int q0w = qt*128 + wave*32;

    __shared__ __align__(16) bf16 kv[2][2][4096];  // [buf][K|V][64 rows x 64]
    __shared__ float ls[4][32];

    // Q as B-operand frags: lane holds Q[q0w+l][h*64 + st*16 + hi*8 + j]
    bf16x8 aq[4];
    {
        const bf16* qrow = qb + ((size_t)(b*1024 + q0w + l))*512 + h*64 + hi*8;
        #pragma unroll
        for (int st=0; st<4; ++st) aq[st] = *(const bf16x8*)(qrow + st*16);
    }

    // staging: slot s (=tid, tid+256) -> row s>>3, granule s&7; global src
    // pre-swizzled so LDS granule g holds global granule g^(row&7)
    const int srow = lane >> 3;             // 0..7
    const int sg   = (lane & 7) ^ srow;     // pre-swizzled granule
    const bf16* kg0 = kb + ((size_t)(b*1024 + wave*8 + srow))*512 + h*64 + sg*8;
    const bf16* vg0 = vT + ((size_t)((b*8 + h)*64 + wave*8 + srow))*1024 + sg*8;

    auto stage = [&](int buf, int t) {
        const size_t ko = (size_t)t*64*512;
        async16p(kg0 + ko,                   &kv[buf][0][wave*512]);
        async16p(kg0 + ko + (size_t)32*512,  &kv[buf][0][2048 + wave*512]);
        async16p(vg0 + t*64,                 &kv[buf][1][wave*512]);
        async16p(vg0 + t*64 + 32*1024,       &kv[buf][1][2048 + wave*512]);
    };

    f32x16 accO[2];
    accO[0] = (f32x16)0.f; accO[1] = (f32x16)0.f;
    float lsum = 0.f;

    stage(0, 0);
    for (int t=0; t<16; ++t) {
        const int cur = t & 1;
        __builtin_amdgcn_sched_barrier(0);
        __builtin_amdgcn_s_barrier();          // all waves done with buf[cur^1]
        if (t < 15) {
            stage(cur ^ 1, t + 1);
            asm volatile("s_waitcnt vmcnt(4)" ::: "memory");  // tile t landed
        } else {
            asm volatile("s_waitcnt vmcnt(0)" ::: "memory");
        }
        __builtin_amdgcn_s_barrier();          // tile t visible

        const bf16* Ks = kv[cur][0];
        const bf16* Vs = kv[cur][1];

        u32x4 paf[4];
        #pragma unroll
        for (int kb2=0; kb2<2; ++kb2) {
            // QK^T swapped: S^T[key=lane&31 block][q col] = K x Q
            f32x16 sT = (f32x16)0.f;
            #pragma unroll
            for (int st=0; st<4; ++st) {
                bf16x8 kf = *(const bf16x8*)(Ks + (kb2*32 + l)*64
                                               + (((st*2 + hi) ^ (l & 7))*8));
                sT = MFMA32(kf, aq[st], sT);
            }
            // exp + per-lane row-sum + pack to bf16 pairs
            unsigned u[8];
            #pragma unroll
            for (int m=0; m<8; ++m) {
                float e0 = __expf(sT[2*m]   * ATT_SCALE);
                float e1 = __expf(sT[2*m+1] * ATT_SCALE);
                lsum += e0 + e1;
                u[m] = pkbf(e0, e1);
            }
            // redistribute to A-frag layout: keys (16sb+hi*8+0..7) per lane
            #pragma unroll
            for (int sb=0; sb<2; ++sb) {
                unsigned a0=u[4*sb], a1=u[4*sb+1], a2=u[4*sb+2], a3=u[4*sb+3];
                plswap(a0, a2);
                plswap(a1, a3);
                paf[kb2*2 + sb] = (u32x4){a0, a1, a2, a3};
            }
        }
        // PV: O[q][d] accumulate
        #pragma unroll
        for (int db=0; db<2; ++db) {
            f32x16 a = accO[db];
            #pragma unroll
            for (int st=0; st<4; ++st) {
                bf16x8 vf = *(const bf16x8*)(Vs + (db*32 + l)*64
                                               + (((st*2 + hi) ^ (l & 7))*8));
                u32x4 pp = paf[st];
                bf16x8 pf = *(bf16x8*)&pp;
                a = MFMA32(pf, vf, a);
            }
            accO[db] = a;
        }
    }

    // combine the two key-halves of l, broadcast per-q via LDS
    lsum += __shfl_xor(lsum, 32);
    ls[wave][l] = lsum;
    __syncthreads();

    #pragma unroll
    for (int g=0; g<4; ++g) {
        f32x4 lv = *(const f32x4*)(&ls[wave][g*8 + hi*4]);
        f32x4 inv;
        #pragma unroll
        for (int i=0;i<4;i++) inv[i] = 1.f / lv[i];
        #pragma unroll
        for (int db=0; db<2; ++db) {
            #pragma unroll
            for (int i=0;i<4;i++) {
                int r = g*4 + i;
                int qrow = q0w + g*8 + hi*4 + i;
                size_t idx = ((size_t)(b*1024 + qrow))*512 + h*64 + db*32 + l;
                float o = accO[db][r] * inv[i] + (float)qb[idx];
                attnb[idx] = (bf16)o;
            }
        }
    }
}

// ---------------- ln0: Obf = LN(attnb)  (attnb already holds q+attn) -------
__global__ __launch_bounds__(256) void ln0_kernel(
    const bf16* __restrict__ attnb, bf16* __restrict__ Obf)
{
    const int wave = threadIdx.x >> 6, lane = threadIdx.x & 63;
    const int row = blockIdx.x*4 + wave;
    const size_t base = (size_t)row*512 + lane*8;
    bf16x8 av = *(const bf16x8*)(attnb + base);
    float x[8];
    #pragma unroll
    for (int i=0;i<8;i++) x[i] = (float)av[i];
    float s1 = 0.f, s2 = 0.f;
    #pragma unroll
    for (int i=0;i<8;i++){ s1 += x[i]; s2 += x[i]*x[i]; }
    #pragma unroll
    for (int off=1; off<64; off<<=1) { s1 += __shfl_xor(s1, off); s2 += __shfl_xor(s2, off); }
    float mu  = s1 * (1.f/512.f);
    float var = s2 * (1.f/512.f) - mu*mu;
    float rstd = rsqrtf(var + 1e-5f);
    bf16x8 ob;
    #pragma unroll
    for (int i=0;i<8;i++) ob[i] = (bf16)((x[i]-mu)*rstd);
    *(bf16x8*)(Obf + base) = ob;
}

// -------- shared GEMM K-loop: 128x128 tile, BK=32 double-buffered ----------
__device__ __forceinline__ void gemm_core(
    const bf16* __restrict__ A, const bf16* __restrict__ BT,
    int m0, int n0, char* smem, f32x4 (&acc)[4][4])
{
    bf16* As = (bf16*)smem;            // 2 x (128x32 = 8 KB)
    bf16* Bs = (bf16*)(smem + 16384);  // 2 x (128x32 = 8 KB)
    const int tid = threadIdx.x;
    const int lane = tid & 63, wave = tid >> 6;
    const int qd = lane >> 4, lr = lane & 15;
    const int wm = (wave & 1) * 64, wn = (wave >> 1) * 64;

    const int srow = tid >> 2;                            // 0..63
    const int sgr  = ((tid & 3) ^ ((tid >> 3) & 3)) * 8;  // pre-swizzled granule
    const bf16* gA = A  + (size_t)(m0 + srow)*512 + sgr;
    const bf16* gB = BT + (size_t)(n0 + srow)*512 + sgr;

    auto stage = [&](int buf, int k0) {
        bf16* lA = As + buf*4096 + wave*512;
        bf16* lB = Bs + buf*4096 + wave*512;
        async16p(gA + k0,                  lA);
        async16p(gA + k0 + (size_t)64*512, lA + 2048);
        async16p(gB + k0,                  lB);
        async16p(gB + k0 + (size_t)64*512, lB + 2048);
    };

    stage(0, 0);
    for (int t = 0; t < 16; ++t) {
        const int cur = t & 1;
        __builtin_amdgcn_sched_barrier(0);
        __builtin_amdgcn_s_barrier();
        if (t < 15) {
            stage(cur ^ 1, (t+1)*32);
            asm volatile("s_waitcnt vmcnt(4)" ::: "memory");
        } else {
            asm volatile("s_waitcnt vmcnt(0)" ::: "memory");
        }
        __builtin_amdgcn_s_barrier();

        const bf16* Ab = As + cur*4096;
        const bf16* Bb = Bs + cur*4096;
        bf16x8 af[4], bfr[4];
        #pragma unroll
        for (int mi=0;mi<4;mi++)
            af[mi] = *(bf16x8*)(Ab + (wm+mi*16+lr)*32 + ((qd^((lr>>1)&3))*8));
        #pragma unroll
        for (int ni=0;ni<4;ni++)
            bfr[ni] = *(bf16x8*)(Bb + (wn+ni*16+lr)*32 + ((qd^((lr>>1)&3))*8));
        #pragma unroll
        for (int mi=0;mi<4;mi++)
          #pragma unroll
          for (int ni=0;ni<4;ni++)
            acc[mi][ni] = MFMA16(af[mi], bfr[ni], acc[mi][ni]);
    }
}

// ------- gemm_o: G = Obf@WoT + bo; xb = Obf + gelu(G)  (bf16 out) ----------
__global__ __launch_bounds__(256, 4) void gemm_o_kernel(
    const bf16* __restrict__ Obf, const bf16* __restrict__ WoT,
    const float* __restrict__ bo, bf16* __restrict__ xb)
{
    __shared__ __align__(16) char smem[32768];
    const int m0 = blockIdx.x * 128, n0 = blockIdx.y * 128;
    const int tid = threadIdx.x;
    const int lane = tid & 63, wave = tid >> 6;
    const int qd = lane >> 4, lr = lane & 15;
    const int wm = (wave & 1) * 64, wn = (wave >> 1) * 64;

    f32x4 acc[4][4];
    #pragma unroll
    for (int i=0;i<4;i++)
      #pragma unroll
      for (int j=0;j<4;j++) acc[i][j] = (f32x4){0,0,0,0};

    gemm_core(Obf, WoT, m0, n0, smem, acc);

    #pragma unroll
    for (int ni=0;ni<4;ni++) {
        int n = n0 + wn + ni*16 + lr;
        float bv = bo[n];
        #pragma unroll
        for (int mi=0;mi<4;mi++) {
            int mb = m0 + wm + mi*16 + qd*4;
            #pragma unroll
            for (int r=0;r<4;r++) {
                float g = acc[mi][ni][r] + bv;
                float gelu = 0.5f * g * (1.f + erff(g * 0.70710678118654752f));
                size_t idx = (size_t)(mb+r)*512 + n;
                xb[idx] = (bf16)((float)Obf[idx] + gelu);
            }
        }
    }
}

// ---------------- ln1: out = LN(xb) ----------------
__global__ __launch_bounds__(256) void ln1_kernel(
    const bf16* __restrict__ xb, float* __restrict__ out)
{
    const int wave = threadIdx.x >> 6, lane = threadIdx.x & 63;
    const int row = blockIdx.x*4 + wave;
    const size_t base = (size_t)row*512 + lane*8;
    bf16x8 xv = *(const bf16x8*)(xb + base);
    float x[8];
    #pragma unroll
    for (int i=0;i<8;i++) x[i] = (float)xv[i];
    float s1 = 0.f, s2 = 0.f;
    #pragma unroll
    for (int i=0;i<8;i++){ s1 += x[i]; s2 += x[i]*x[i]; }
    #pragma unroll
    for (int off=1; off<64; off<<=1) { s1 += __shfl_xor(s1, off); s2 += __shfl_xor(s2, off); }
    float mu  = s1 * (1.f/512.f);
    float var = s2 * (1.f/512.f) - mu*mu;
    float rstd = rsqrtf(var + 1e-5f);
    float4 o0 = {(x[0]-mu)*rstd,(x[1]-mu)*rstd,(x[2]-mu)*rstd,(x[3]-mu)*rstd};
    float4 o1 = {(x[4]-mu)*rstd,(x[5]-mu)*rstd,(x[6]-mu)*rstd,(x[7]-mu)*rstd};
    *(float4*)(out + base)     = o0;
    *(float4*)(out + base + 4) = o1;
}

extern "C" void kernel_launch(void* const* d_in, const int* in_sizes, int n_in,
                              void* d_out, int out_size, void* d_ws, size_t ws_size,
                              hipStream_t stream)
{
    (void)in_sizes; (void)n_in; (void)out_size; (void)ws_size;
    const float* Q  = (const float*)d_in[0];
    const float* K  = (const float*)d_in[1];
    const float* Wq = (const float*)d_in[2];
    const float* bq = (const float*)d_in[3];
    const float* Wk = (const float*)d_in[4];
    const float* bk = (const float*)d_in[5];
    const float* Wv = (const float*)d_in[6];
    const float* bv = (const float*)d_in[7];
    const float* Wo = (const float*)d_in[8];
    const float* bo = (const float*)d_in[9];
    float* out = (float*)d_out;

    const size_t nTok = (size_t)16*1024*512;
    char* p = (char*)d_ws;
    auto alloc = [&](size_t bytes)->char* {
        char* r = p; p += (bytes + 255) & ~(size_t)255; return r;
    };
    bf16* WqT   = (bf16*)alloc(512*512*2);
    bf16* WkT   = (bf16*)alloc(512*512*2);
    bf16* WvT   = (bf16*)alloc(512*512*2);
    bf16* WoT   = (bf16*)alloc(512*512*2);
    bf16* qbb   = (bf16*)alloc(nTok*2);
    bf16* kbb   = (bf16*)alloc(nTok*2);
    bf16* vT    = (bf16*)alloc(nTok*2);
    bf16* attnb = (bf16*)alloc(nTok*2);
    bf16* Obf   = (bf16*)alloc(nTok*2);
    bf16* xb    = (bf16*)alloc(nTok*2);

    prep_w_kernel<<<1024, 256, 0, stream>>>(Wq, Wk, Wv, Wo, WqT, WkT, WvT, WoT);
    gemm_qkv_kernel<<<dim3(128,4,3), 256, 0, stream>>>(Q, K, WqT, WkT, WvT,
                                                       bq, bk, bv, qbb, kbb, vT);
    attn_kernel<<<dim3(1024), 256, 0, stream>>>(qbb, kbb, vT, attnb);
    ln0_kernel<<<4096, 256, 0, stream>>>(attnb, Obf);
    gemm_o_kernel<<<dim3(128,4), 256, 0, stream>>>(Obf, WoT, bo, xb);
    ln1_kernel<<<4096, 256, 0, stream>>>(xb, out);
}

// Round 3
// 251.519 us; speedup vs baseline: 1.0792x; 1.0235x over previous
//
#include <hip/hip_runtime.h>
#include <hip/hip_bf16.h>
#include <math.h>

typedef __bf16 bf16;
typedef __bf16 bf16x8 __attribute__((ext_vector_type(8)));
typedef float  f32x4  __attribute__((ext_vector_type(4)));
typedef float  f32x16 __attribute__((ext_vector_type(16)));
typedef unsigned u32x4 __attribute__((ext_vector_type(4)));

#define MFMA16(a,b,c) __builtin_amdgcn_mfma_f32_16x16x32_bf16((a),(b),(c),0,0,0)
#define MFMA32(a,b,c) __builtin_amdgcn_mfma_f32_32x32x16_bf16((a),(b),(c),0,0,0)
/* k is pre-scaled by 1/sqrt(512)*log2(e) in the projection epilogue,
   so attention uses exp2 directly. */
#define KSCALE 0.0637587159f

__device__ __forceinline__ void async16p(const void* g, void* l) {
    __builtin_amdgcn_global_load_lds((const __attribute__((address_space(1))) void*)g,
                                     (__attribute__((address_space(3))) void*)l,
                                     16, 0, 0);
}

__device__ __forceinline__ float fexp2(float x) {
#if __has_builtin(__builtin_amdgcn_exp2f)
    return __builtin_amdgcn_exp2f(x);
#else
    return exp2f(x);
#endif
}

__device__ __forceinline__ unsigned pkbf(float a, float b) {
    union { bf16 h[2]; unsigned u; } x;
    x.h[0] = (bf16)a; x.h[1] = (bf16)b; return x.u;
}

__device__ __forceinline__ void plswap(unsigned &a, unsigned &b) {
#if __has_builtin(__builtin_amdgcn_permlane32_swap)
    auto r = __builtin_amdgcn_permlane32_swap((int)a, (int)b, false, false);
    a = (unsigned)r[0]; b = (unsigned)r[1];
#else
    unsigned sa = (unsigned)__shfl_xor((int)a, 32);
    unsigned sb = (unsigned)__shfl_xor((int)b, 32);
    bool hi = (threadIdx.x & 32) != 0;
    unsigned na = hi ? sb : a;
    unsigned nb = hi ? b  : sa;
    a = na; b = nb;
#endif
}

// ---------------- prep: transpose 4 weights fp32[k][n] -> bf16 T[n][k] -----
__global__ __launch_bounds__(256) void prep_w_kernel(
    const float* __restrict__ Wq, const float* __restrict__ Wk,
    const float* __restrict__ Wv, const float* __restrict__ Wo,
    bf16* __restrict__ WqT, bf16* __restrict__ WkT,
    bf16* __restrict__ WvT, bf16* __restrict__ WoT)
{
    __shared__ float tile[32][33];
    const int bx = blockIdx.x;
    const float* W; bf16* T;
    switch (bx >> 8) {
      case 0: W=Wq; T=WqT; break;
      case 1: W=Wk; T=WkT; break;
      case 2: W=Wv; T=WvT; break;
      default: W=Wo; T=WoT; break;
    }
    const int rest = bx & 255;
    const int k0 = (rest & 15) * 32, n0 = (rest >> 4) * 32;
    const int tx = threadIdx.x & 31, ty = threadIdx.x >> 5;
    #pragma unroll
    for (int i=0;i<32;i+=8)
        tile[ty+i][tx] = W[(size_t)(k0+ty+i)*512 + n0+tx];
    __syncthreads();
    #pragma unroll
    for (int i=0;i<32;i+=8)
        T[(size_t)(n0+ty+i)*512 + k0+tx] = (bf16)tile[tx][ty+i];
}

// ------------- fused projection GEMM: one staged A-tile -> TWO outputs -----
// Blocks x<256 (Q-type): q for n-tiles {n0, n0+256} from one Q tile.
// Blocks x>=256 (KV-type): k (scaled by KSCALE) and v from one K tile.
// 128x128 tiles, BK=32, dbuf LDS (64 KB), counted vmcnt(8); 32 MFMA/phase.
__global__ __launch_bounds__(256, 2) void gemm_proj_kernel(
    const float* __restrict__ Qf, const float* __restrict__ Kf,
    const bf16* __restrict__ WqT, const bf16* __restrict__ WkT,
    const bf16* __restrict__ WvT,
    const float* __restrict__ bq, const float* __restrict__ bk,
    const float* __restrict__ bv,
    bf16* __restrict__ qbb, bf16* __restrict__ kbb, bf16* __restrict__ vT)
{
    __shared__ __align__(16) char smem[65536];
    float* As32 = (float*)smem;            // [buf][128][32] fp32 (2x16 KB)
    bf16*  Bs   = (bf16*)(smem + 32768);   // [buf][p][128][32] bf16 (2x16 KB)
    bf16*  Lt   = (bf16*)smem;             // epilogue overlay (buf0 region)

    const int x = blockIdx.x;
    const bool isQ = (x < 256);
    int m0, n0;
    const float* A; const bf16 *BT0, *BT1; const float *bb0, *bb1;
    if (isQ) {
        m0 = (x >> 1) * 128; n0 = (x & 1) * 128;
        A = Qf; BT0 = WqT + (size_t)n0*512; BT1 = WqT + (size_t)(n0+256)*512;
        bb0 = bq + n0; bb1 = bq + n0 + 256;
    } else {
        int r = x - 256;
        m0 = (r >> 2) * 128; n0 = (r & 3) * 128;
        A = Kf; BT0 = WkT + (size_t)n0*512; BT1 = WvT + (size_t)n0*512;
        bb0 = bk + n0; bb1 = bv + n0;
    }

    const int tid = threadIdx.x;
    const int lane = tid & 63, wave = tid >> 6;
    const int qd = lane >> 4, lr = lane & 15;
    const int wm = (wave & 1) * 64, wn = (wave >> 1) * 64;

    const float* gA = A + (size_t)(m0 + (tid>>3))*512 + (((tid&7)^((tid>>3)&7))*4);
    const int bgr = ((tid & 3) ^ ((tid >> 3) & 3)) * 8;   // key (row>>1)&3
    const bf16* gB0 = BT0 + (size_t)(tid>>2)*512 + bgr;
    const bf16* gB1 = BT1 + (size_t)(tid>>2)*512 + bgr;

    f32x4 acc[2][4][4];
    #pragma unroll
    for (int p=0;p<2;p++)
      #pragma unroll
      for (int i=0;i<4;i++)
        #pragma unroll
        for (int j=0;j<4;j++) acc[p][i][j] = (f32x4){0,0,0,0};

    auto stage = [&](int buf, int k0) {
        float* lA = As32 + buf*4096 + wave*256;
        #pragma unroll
        for (int i=0;i<4;i++)
            async16p(gA + k0 + (size_t)i*32*512, lA + i*1024);
        bf16* lB0 = Bs + buf*8192 + wave*512;
        async16p(gB0 + k0,                  lB0);
        async16p(gB0 + k0 + (size_t)64*512, lB0 + 2048);
        bf16* lB1 = Bs + buf*8192 + 4096 + wave*512;
        async16p(gB1 + k0,                  lB1);
        async16p(gB1 + k0 + (size_t)64*512, lB1 + 2048);
    };

    stage(0, 0);
    for (int t = 0; t < 16; ++t) {
        const int cur = t & 1;
        __builtin_amdgcn_sched_barrier(0);
        __builtin_amdgcn_s_barrier();
        if (t < 15) {
            stage(cur ^ 1, (t+1)*32);
            asm volatile("s_waitcnt vmcnt(8)" ::: "memory");
        } else {
            asm volatile("s_waitcnt vmcnt(0)" ::: "memory");
        }
        __builtin_amdgcn_s_barrier();

        const float* Ab = As32 + cur*4096;
        const bf16*  Bb = Bs   + cur*8192;
        bf16x8 af[4], bfr[2][4];
        #pragma unroll
        for (int mi=0;mi<4;mi++) {
            int row = wm + mi*16 + lr;
            f32x4 f0 = *(f32x4*)(Ab + row*32 + (((qd*2  )^(lr&7))*4));
            f32x4 f1 = *(f32x4*)(Ab + row*32 + (((qd*2+1)^(lr&7))*4));
            bf16x8 a;
            a[0]=(bf16)f0[0]; a[1]=(bf16)f0[1]; a[2]=(bf16)f0[2]; a[3]=(bf16)f0[3];
            a[4]=(bf16)f1[0]; a[5]=(bf16)f1[1]; a[6]=(bf16)f1[2]; a[7]=(bf16)f1[3];
            af[mi] = a;
        }
        #pragma unroll
        for (int p=0;p<2;p++)
          #pragma unroll
          for (int ni=0;ni<4;ni++)
            bfr[p][ni] = *(bf16x8*)(Bb + p*4096 + (wn+ni*16+lr)*32
                                       + ((qd^((lr>>1)&3))*8));
        #pragma unroll
        for (int p=0;p<2;p++)
          #pragma unroll
          for (int mi=0;mi<4;mi++)
            #pragma unroll
            for (int ni=0;ni<4;ni++)
              acc[p][mi][ni] = MFMA16(af[mi], bfr[p][ni], acc[p][mi][ni]);
    }

    if (isQ) {
        #pragma unroll
        for (int p=0;p<2;p++) {
            const float* bb = p ? bb1 : bb0;
            #pragma unroll
            for (int ni=0;ni<4;ni++) {
                int nl = wn + ni*16 + lr;
                int n = n0 + p*256 + nl;
                float bv0 = bb[nl];
                #pragma unroll
                for (int mi=0;mi<4;mi++) {
                    int mb = m0 + wm + mi*16 + qd*4;
                    #pragma unroll
                    for (int r=0;r<4;r++)
                        qbb[(size_t)(mb+r)*512 + n] = (bf16)(acc[p][mi][ni][r] + bv0);
                }
            }
        }
    } else {
        // k: scaled write
        #pragma unroll
        for (int ni=0;ni<4;ni++) {
            int nl = wn + ni*16 + lr;
            int n = n0 + nl;
            float bv0 = bb0[nl];
            #pragma unroll
            for (int mi=0;mi<4;mi++) {
                int mb = m0 + wm + mi*16 + qd*4;
                #pragma unroll
                for (int r=0;r<4;r++)
                    kbb[(size_t)(mb+r)*512 + n] = (bf16)((acc[0][mi][ni][r] + bv0)*KSCALE);
            }
        }
        // v: vT[b][h][d][tok] via swizzled LDS transpose (acc[1])
        const int b = m0 >> 10, tok0 = m0 & 1023;
        const int row = tid >> 2, ch = tid & 3;
        #pragma unroll
        for (int half = 0; half < 2; ++half) {
            __syncthreads();
            if ((wn >> 6) == half) {
                #pragma unroll
                for (int ni=0;ni<4;ni++) {
                    int nl = ni*16 + lr;
                    float bvv = bb1[half*64 + nl];
                    #pragma unroll
                    for (int mi=0;mi<4;mi++)
                      #pragma unroll
                      for (int r=0;r<4;r++) {
                        int col = wm + mi*16 + qd*4 + r;
                        Lt[nl*128 + ((((col>>3)^(nl&7))<<3) | (col&7))]
                            = (bf16)(acc[1][mi][ni][r] + bvv);
                      }
                }
            }
            __syncthreads();
            const int h = (n0 >> 6) + half;
            bf16* dst = vT + ((size_t)((b*8 + h)*64 + row))*1024 + tok0 + ch*32;
            #pragma unroll
            for (int s=0;s<4;s++) {
                int g = (ch*4 + s) ^ (row & 7);
                *(uint4*)(dst + s*8) = *(uint4*)(Lt + row*128 + g*8);
            }
        }
    }
}

// ---------------- attention: swapped-QK^T 32x32, in-register softmax -------
// k pre-scaled -> P = exp2(sT). LDS key (row&7)^(row>>3) kills the 4-way
// bank conflict (rows are 128B-aligned). setprio(1) around MFMA clusters.
__global__ __launch_bounds__(256, 4) void attn_kernel(
    const bf16* __restrict__ qb, const bf16* __restrict__ kb,
    const bf16* __restrict__ vT, bf16* __restrict__ attnb)
{
    const int x = blockIdx.x;
    const int qt = x >> 7, h = x & 7, b = (x & 127) >> 3;
    const int tid = threadIdx.x, lane = tid & 63, wave = tid >> 6;
    const int l = lane & 31, hi = lane >> 5;
    const int q0w = qt*128 + wave*32;

    __shared__ __align__(16) bf16 kv[2][2][4096];  // [buf][K|V][64 x 64]
    __shared__ float ls[4][32];

    bf16x8 aq[4];
    {
        const bf16* qrow = qb + ((size_t)(b*1024 + q0w + l))*512 + h*64 + hi*8;
        #pragma unroll
        for (int st=0; st<4; ++st) aq[st] = *(const bf16x8*)(qrow + st*16);
    }

    // staging with key(row) = (row&7)^(row>>3): row = wave*8+srow (+32)
    const int srow = lane >> 3;                 // 0..7
    const int sgA  = (lane & 7) ^ srow ^ wave;  // pre-swizzled granule
    const int sgB  = sgA ^ 4;                   // rows +32: key ^= 4
    const bf16* kg0 = kb + ((size_t)(b*1024 + wave*8 + srow))*512      + h*64 + sgA*8;
    const bf16* kg1 = kb + ((size_t)(b*1024 + wave*8 + srow + 32))*512 + h*64 + sgB*8;
    const bf16* vg0 = vT + ((size_t)((b*8 + h)*64 + wave*8 + srow))*1024      + sgA*8;
    const bf16* vg1 = vT + ((size_t)((b*8 + h)*64 + wave*8 + srow + 32))*1024 + sgB*8;

    auto stage = [&](int buf, int t) {
        const size_t ko = (size_t)t*64*512;
        async16p(kg0 + ko,     &kv[buf][0][wave*512]);
        async16p(kg1 + ko,     &kv[buf][0][2048 + wave*512]);
        async16p(vg0 + t*64,   &kv[buf][1][wave*512]);
        async16p(vg1 + t*64,   &kv[buf][1][2048 + wave*512]);
    };

    f32x16 accO[2];
    accO[0] = (f32x16)0.f; accO[1] = (f32x16)0.f;
    float lsum = 0.f;
    const int kx = (l & 7) ^ (l >> 3);   // read-side lane key component

    stage(0, 0);
    for (int t=0; t<16; ++t) {
        const int cur = t & 1;
        __builtin_amdgcn_sched_barrier(0);
        __builtin_amdgcn_s_barrier();
        if (t < 15) {
            stage(cur ^ 1, t + 1);
            asm volatile("s_waitcnt vmcnt(4)" ::: "memory");
        } else {
            asm volatile("s_waitcnt vmcnt(0)" ::: "memory");
        }
        __builtin_amdgcn_s_barrier();

        const bf16* Ks = kv[cur][0];
        const bf16* Vs = kv[cur][1];

        u32x4 paf[4];
        #pragma unroll
        for (int kb2=0; kb2<2; ++kb2) {
            f32x16 sT = (f32x16)0.f;
            __builtin_amdgcn_s_setprio(1);
            #pragma unroll
            for (int st=0; st<4; ++st) {
                bf16x8 kf = *(const bf16x8*)(Ks + (kb2*32 + l)*64
                               + (((st*2 + hi) ^ kx ^ (kb2<<2))*8));
                sT = MFMA32(kf, aq[st], sT);
            }
            __builtin_amdgcn_s_setprio(0);
            unsigned u[8];
            #pragma unroll
            for (int m=0; m<8; ++m) {
                float e0 = fexp2(sT[2*m]);
                float e1 = fexp2(sT[2*m+1]);
                lsum += e0 + e1;
                u[m] = pkbf(e0, e1);
            }
            #pragma unroll
            for (int sb=0; sb<2; ++sb) {
                unsigned a0=u[4*sb], a1=u[4*sb+1], a2=u[4*sb+2], a3=u[4*sb+3];
                plswap(a0, a2);
                plswap(a1, a3);
                paf[kb2*2 + sb] = (u32x4){a0, a1, a2, a3};
            }
        }
        __builtin_amdgcn_s_setprio(1);
        #pragma unroll
        for (int db=0; db<2; ++db) {
            f32x16 a = accO[db];
            #pragma unroll
            for (int st=0; st<4; ++st) {
                bf16x8 vf = *(const bf16x8*)(Vs + (db*32 + l)*64
                               + (((st*2 + hi) ^ kx ^ (db<<2))*8));
                u32x4 pp = paf[st];
                bf16x8 pf = *(bf16x8*)&pp;
                a = MFMA32(pf, vf, a);
            }
            accO[db] = a;
        }
        __builtin_amdgcn_s_setprio(0);
    }

    lsum += __shfl_xor(lsum, 32);
    ls[wave][l] = lsum;
    __syncthreads();

    #pragma unroll
    for (int g=0; g<4; ++g) {
        f32x4 lv = *(const f32x4*)(&ls[wave][g*8 + hi*4]);
        f32x4 inv;
        #pragma unroll
        for (int i=0;i<4;i++) inv[i] = 1.f / lv[i];
        #pragma unroll
        for (int db=0; db<2; ++db) {
            #pragma unroll
            for (int i=0;i<4;i++) {
                int r = g*4 + i;
                int qrow = q0w + g*8 + hi*4 + i;
                size_t idx = ((size_t)(b*1024 + qrow))*512 + h*64 + db*32 + l;
                float o = accO[db][r] * inv[i] + (float)qb[idx];
                attnb[idx] = (bf16)o;
            }
        }
    }
}

// ---------------- ln0: Obf = LN(attnb) ----------------
__global__ __launch_bounds__(256) void ln0_kernel(
    const bf16* __restrict__ attnb, bf16* __restrict__ Obf)
{
    const int wave = threadIdx.x >> 6, lane = threadIdx.x & 63;
    const int row = blockIdx.x*4 + wave;
    const size_t base = (size_t)row*512 + lane*8;
    bf16x8 av = *(const bf16x8*)(attnb + base);
    float x[8];
    #pragma unroll
    for (int i=0;i<8;i++) x[i] = (float)av[i];
    float s1 = 0.f, s2 = 0.f;
    #pragma unroll
    for (int i=0;i<8;i++){ s1 += x[i]; s2 += x[i]*x[i]; }
    #pragma unroll
    for (int off=1; off<64; off<<=1) { s1 += __shfl_xor(s1, off); s2 += __shfl_xor(s2, off); }
    float mu  = s1 * (1.f/512.f);
    float var = s2 * (1.f/512.f) - mu*mu;
    float rstd = rsqrtf(var + 1e-5f);
    bf16x8 ob;
    #pragma unroll
    for (int i=0;i<8;i++) ob[i] = (bf16)((x[i]-mu)*rstd);
    *(bf16x8*)(Obf + base) = ob;
}

// ------- gemm_o: 64x128 tiles (grid 1024 -> 4 blocks/CU), BK=32 dbuf -------
__global__ __launch_bounds__(256, 4) void gemm_o_kernel(
    const bf16* __restrict__ Obf, const bf16* __restrict__ WoT,
    const float* __restrict__ bo, bf16* __restrict__ xb)
{
    __shared__ __align__(16) char smem[24576];
    bf16* As = (bf16*)smem;            // [buf][64][32]  (2x4 KB)
    bf16* Bs = (bf16*)(smem + 8192);   // [buf][128][32] (2x8 KB)
    const int m0 = blockIdx.x * 64, n0 = blockIdx.y * 128;
    const int tid = threadIdx.x;
    const int lane = tid & 63, wave = tid >> 6;
    const int qd = lane >> 4, lr = lane & 15;
    const int wm = (wave & 1) * 32, wn = (wave >> 1) * 64;

    const int bgr = ((tid & 3) ^ ((tid >> 3) & 3)) * 8;   // key (row>>1)&3
    const bf16* gA = Obf + (size_t)(m0 + (tid>>2))*512 + bgr;
    const bf16* gB = WoT + (size_t)(n0 + (tid>>2))*512 + bgr;

    f32x4 acc[2][4];
    #pragma unroll
    for (int i=0;i<2;i++)
      #pragma unroll
      for (int j=0;j<4;j++) acc[i][j] = (f32x4){0,0,0,0};

    auto stage = [&](int buf, int k0) {
        async16p(gA + k0,                  As + buf*2048 + wave*512);
        bf16* lB = Bs + buf*4096 + wave*512;
        async16p(gB + k0,                  lB);
        async16p(gB + k0 + (size_t)64*512, lB + 2048);
    };

    stage(0, 0);
    for (int t = 0; t < 16; ++t) {
        const int cur = t & 1;
        __builtin_amdgcn_sched_barrier(0);
        __builtin_amdgcn_s_barrier();
        if (t < 15) {
            stage(cur ^ 1, (t+1)*32);
            asm volatile("s_waitcnt vmcnt(3)" ::: "memory");
        } else {
            asm volatile("s_waitcnt vmcnt(0)" ::: "memory");
        }
        __builtin_amdgcn_s_barrier();

        const bf16* Ab = As + cur*2048;
        const bf16* Bb = Bs + cur*4096;
        bf16x8 af[2], bfr[4];
        #pragma unroll
        for (int mi=0;mi<2;mi++)
            af[mi] = *(bf16x8*)(Ab + (wm+mi*16+lr)*32 + ((qd^((lr>>1)&3))*8));
        #pragma unroll
        for (int ni=0;ni<4;ni++)
            bfr[ni] = *(bf16x8*)(Bb + (wn+ni*16+lr)*32 + ((qd^((lr>>1)&3))*8));
        #pragma unroll
        for (int mi=0;mi<2;mi++)
          #pragma unroll
          for (int ni=0;ni<4;ni++)
            acc[mi][ni] = MFMA16(af[mi], bfr[ni], acc[mi][ni]);
    }

    #pragma unroll
    for (int ni=0;ni<4;ni++) {
        int n = n0 + wn + ni*16 + lr;
        float bv = bo[n];
        #pragma unroll
        for (int mi=0;mi<2;mi++) {
            int mb = m0 + wm + mi*16 + qd*4;
            #pragma unroll
            for (int r=0;r<4;r++) {
                float g = acc[mi][ni][r] + bv;
                float gelu = 0.5f * g * (1.f + erff(g * 0.70710678118654752f));
                size_t idx = (size_t)(mb+r)*512 + n;
                xb[idx] = (bf16)((float)Obf[idx] + gelu);
            }
        }
    }
}

// ---------------- ln1: out = LN(xb) ----------------
__global__ __launch_bounds__(256) void ln1_kernel(
    const bf16* __restrict__ xb, float* __restrict__ out)
{
    const int wave = threadIdx.x >> 6, lane = threadIdx.x & 63;
    const int row = blockIdx.x*4 + wave;
    const size_t base = (size_t)row*512 + lane*8;
    bf16x8 xv = *(const bf16x8*)(xb + base);
    float x[8];
    #pragma unroll
    for (int i=0;i<8;i++) x[i] = (float)xv[i];
    float s1 = 0.f, s2 = 0.f;
    #pragma unroll
    for (int i=0;i<8;i++){ s1 += x[i]; s2 += x[i]*x[i]; }
    #pragma unroll
    for (int off=1; off<64; off<<=1) { s1 += __shfl_xor(s1, off); s2 += __shfl_xor(s2, off); }
    float mu  = s1 * (1.f/512.f);
    float var = s2 * (1.f/512.f) - mu*mu;
    float rstd = rsqrtf(var + 1e-5f);
    float4 o0 = {(x[0]-mu)*rstd,(x[1]-mu)*rstd,(x[2]-mu)*rstd,(x[3]-mu)*rstd};
    float4 o1 = {(x[4]-mu)*rstd,(x[5]-mu)*rstd,(x[6]-mu)*rstd,(x[7]-mu)*rstd};
    *(float4*)(out + base)     = o0;
    *(float4*)(out + base + 4) = o1;
}

extern "C" void kernel_launch(void* const* d_in, const int* in_sizes, int n_in,
                              void* d_out, int out_size, void* d_ws, size_t ws_size,
                              hipStream_t stream)
{
    (void)in_sizes; (void)n_in; (void)out_size; (void)ws_size;
    const float* Q  = (const float*)d_in[0];
    const float* K  = (const float*)d_in[1];
    const float* Wq = (const float*)d_in[2];
    const float* bq = (const float*)d_in[3];
    const float* Wk = (const float*)d_in[4];
    const float* bk = (const float*)d_in[5];
    const float* Wv = (const float*)d_in[6];
    const float* bv = (const float*)d_in[7];
    const float* Wo = (const float*)d_in[8];
    const float* bo = (const float*)d_in[9];
    float* out = (float*)d_out;

    const size_t nTok = (size_t)16*1024*512;
    char* p = (char*)d_ws;
    auto alloc = [&](size_t bytes)->char* {
        char* r = p; p += (bytes + 255) & ~(size_t)255; return r;
    };
    bf16* WqT   = (bf16*)alloc(512*512*2);
    bf16* WkT   = (bf16*)alloc(512*512*2);
    bf16* WvT   = (bf16*)alloc(512*512*2);
    bf16* WoT   = (bf16*)alloc(512*512*2);
    bf16* qbb   = (bf16*)alloc(nTok*2);
    bf16* kbb   = (bf16*)alloc(nTok*2);
    bf16* vT    = (bf16*)alloc(nTok*2);
    bf16* attnb = (bf16*)alloc(nTok*2);
    bf16* Obf   = (bf16*)alloc(nTok*2);
    bf16* xb    = (bf16*)alloc(nTok*2);

    prep_w_kernel<<<1024, 256, 0, stream>>>(Wq, Wk, Wv, Wo, WqT, WkT, WvT, WoT);
    gemm_proj_kernel<<<768, 256, 0, stream>>>(Q, K, WqT, WkT, WvT,
                                              bq, bk, bv, qbb, kbb, vT);
    attn_kernel<<<dim3(1024), 256, 0, stream>>>(qbb, kbb, vT, attnb);
    ln0_kernel<<<4096, 256, 0, stream>>>(attnb, Obf);
    gemm_o_kernel<<<dim3(256,4), 256, 0, stream>>>(Obf, WoT, bo, xb);
    ln1_kernel<<<4096, 256, 0, stream>>>(xb, out);
}